// Round 12
// baseline (534.501 us; speedup 1.0000x reference)
//
#include <hip/hip_runtime.h>

#define DD 128

using bf16 = __bf16;
typedef __bf16 bf16x8 __attribute__((ext_vector_type(8)));
typedef float f32x4 __attribute__((ext_vector_type(4)));

__device__ inline bf16x8 cvt8(const float* p) {
  f32x4 v0 = *(const f32x4*)p;
  f32x4 v1 = *(const f32x4*)(p + 4);
  bf16x8 r;
  r[0] = (bf16)v0[0]; r[1] = (bf16)v0[1]; r[2] = (bf16)v0[2]; r[3] = (bf16)v0[3];
  r[4] = (bf16)v1[0]; r[5] = (bf16)v1[1]; r[6] = (bf16)v1[2]; r[7] = (bf16)v1[3];
  return r;
}

// fast tanh: 1 - 2/(e^{2x}+1); v_exp + v_rcp, saturates correctly at +-1
__device__ inline float ftanh(float x) {
  float e2 = __expf(2.0f * x);
  return 1.0f - 2.0f * __builtin_amdgcn_rcpf(e2 + 1.0f);
}

// XOR swizzle for [128 rows][256 B] LDS tiles (G4)
__device__ inline int swz(int o) { return o ^ (((o >> 8) & 7) << 4); }

// ---- fused prologue: zero cnt+dbin | weights->bf16 | x->bf16 -------------
__global__ void k_prep(int* __restrict__ cnt, int* __restrict__ dbin, int N,
                       const float* __restrict__ w0, const float* __restrict__ w1,
                       const float* __restrict__ w2, const float* __restrict__ w3,
                       const float* __restrict__ w4, bf16* __restrict__ wb, int totalW,
                       const float* __restrict__ x, bf16* __restrict__ xb, int total8,
                       int nbZ, int nbW) {
  int b = blockIdx.x;
  if (b == 0 && threadIdx.x < 64) dbin[threadIdx.x] = 0;
  if (b < nbZ) {
    int i = b * 256 + threadIdx.x;
    if (i < N) cnt[i] = 0;
  } else if (b < nbZ + nbW) {
    int i = (b - nbZ) * 256 + threadIdx.x;
    if (i < totalW) {
      int m = i >> 14;           // DD*DD = 16384
      int r = i & 16383;
      const float* s = m == 0 ? w0 : m == 1 ? w1 : m == 2 ? w2 : m == 3 ? w3 : w4;
      wb[i] = (bf16)s[r];
    }
  } else {
    int i = (b - nbZ - nbW) * 256 + threadIdx.x;
    if (i < total8) *(bf16x8*)(xb + (size_t)i * 8) = cvt8(x + (size_t)i * 8);
  }
}

// ---- CSR build ----------------------------------------------------------
__global__ void k_hist(const int* __restrict__ dst, int* __restrict__ cnt, int E) {
  int e = blockIdx.x * 256 + threadIdx.x;
  if (e < E) atomicAdd(&cnt[dst[e]], 1);
}

__global__ __launch_bounds__(256) void k_scan1(const int* __restrict__ cnt,
                                               int* __restrict__ bsum, int N) {
  __shared__ int sm[256];
  int t = threadIdx.x;
  int i = blockIdx.x * 256 + t;
  sm[t] = (i < N) ? cnt[i] : 0;
  __syncthreads();
#pragma unroll
  for (int d = 128; d > 0; d >>= 1) {
    if (t < d) sm[t] += sm[t + d];
    __syncthreads();
  }
  if (t == 0) bsum[blockIdx.x] = sm[0];
}

__global__ __launch_bounds__(256) void k_scan2(int* __restrict__ bsum, int nb) {
  __shared__ int sm[256];
  int t = threadIdx.x;
  int v = (t < nb) ? bsum[t] : 0;
  sm[t] = v;
  __syncthreads();
#pragma unroll
  for (int d = 1; d < 256; d <<= 1) {
    int u = (t >= d) ? sm[t - d] : 0;
    __syncthreads();
    sm[t] += u;
    __syncthreads();
  }
  if (t < nb) bsum[t] = sm[t] - v;   // exclusive prefix
}

__global__ __launch_bounds__(256) void k_scan3(const int* __restrict__ cnt,
                                               const int* __restrict__ bsum,
                                               int* __restrict__ offs,
                                               int* __restrict__ cursor, int N) {
  __shared__ int sm[256];
  int t = threadIdx.x;
  int i = blockIdx.x * 256 + t;
  int v = (i < N) ? cnt[i] : 0;
  sm[t] = v;
  __syncthreads();
#pragma unroll
  for (int d = 1; d < 256; d <<= 1) {
    int u = (t >= d) ? sm[t - d] : 0;
    __syncthreads();
    sm[t] += u;
    __syncthreads();
  }
  int incl = sm[t];
  int base = bsum[blockIdx.x];
  if (i < N) {
    int ex = base + incl - v;
    offs[i] = ex;
    cursor[i] = ex;
    if (i == N - 1) offs[N] = base + incl;
  }
}

__global__ void k_scatter(const int* __restrict__ src, const int* __restrict__ dst,
                          int* __restrict__ cursor, int* __restrict__ ssrc, int E) {
  int e = blockIdx.x * 256 + threadIdx.x;
  if (e < E) {
    int d = dst[e];
    int p = atomicAdd(&cursor[d], 1);
    ssrc[p] = src[e];
  }
}

// ---- degree sort (counting sort, 64 buckets, DESCENDING degree) ---------
__global__ void k_dhist(const int* __restrict__ cnt, int* __restrict__ dbin, int N) {
  int i = blockIdx.x * 256 + threadIdx.x;
  if (i < N) atomicAdd(&dbin[min(cnt[i], 63)], 1);
}

__global__ void k_dscan(const int* __restrict__ dbin, int* __restrict__ dcur) {
  int t = threadIdx.x;           // 64 threads
  int s = 0;
  for (int b = t + 1; b < 64; ++b) s += dbin[b];   // sum of higher buckets
  dcur[t] = s;                   // bucket 63 (heaviest) starts at 0
}

__global__ void k_dperm(const int* __restrict__ cnt, int* __restrict__ dcur,
                        int* __restrict__ perm, int N) {
  int i = blockIdx.x * 256 + threadIdx.x;
  if (i < N) {
    int b = min(cnt[i], 63);
    int p = atomicAdd(&dcur[b], 1);
    perm[p] = i;
  }
}

// ---- fused SAGE layer: aggregate + GEMM, degree-sorted ------------------
// Block = 1024 threads (16 waves), Ws+Wn staged in 64 KB swizzled LDS.
// Wave w handles nodes perm[tile*16 .. tile*16+15] (degree-homogeneous).
// MODE 0: H1out[perm-row] = (bf16)v
// MODE 1: Resb[perm-row] = (bf16)(Xres + h1 + 0.5*v)   (res, bf16)
template <int MODE>
__global__ __launch_bounds__(1024, 1) void k_layer(const bf16* __restrict__ Hb,
                                                   const int* __restrict__ offs,
                                                   const int* __restrict__ ssrc,
                                                   const int* __restrict__ perm,
                                                   const bf16* __restrict__ Wsb,
                                                   const bf16* __restrict__ Wnb,
                                                   const float* __restrict__ bias,
                                                   const float* __restrict__ Xres,
                                                   bf16* __restrict__ H1out,
                                                   bf16* __restrict__ Resb, int N) {
  __shared__ char smem[65536];   // [2][128 rows][256 B], swizzled
  int t = threadIdx.x;
#pragma unroll
  for (int m = 0; m < 2; ++m) {
    const bf16* wsrc = m ? Wnb : Wsb;
#pragma unroll
    for (int it = 0; it < 2; ++it) {
      int o = (it * 1024 + t) * 16;         // linear byte offset in matrix
      *(bf16x8*)(smem + m * 32768 + swz(o)) = *(const bf16x8*)(wsrc + o / 2);
    }
  }
  __syncthreads();

  int wv = t >> 6;
  int lane = t & 63;
  int tile = blockIdx.x * 16 + wv;
  int n0 = tile << 4;
  if (n0 >= N) return;
  int lr = lane & 15;
  int g = lane >> 4;
  int lk = g << 3;                          // k offset in elems (8-elem chunk)

  int node = perm[n0 + lr];                 // degree-sorted node id

  // A1 (self) fragments
  const bf16* a1p = Hb + (size_t)node * DD + lk;
  bf16x8 a1[4];
#pragma unroll
  for (int kk = 0; kk < 4; ++kk) a1[kk] = *(const bf16x8*)(a1p + kk * 32);

  // aggregate neighbor mean into A2 fragments (f32 acc)
  int beg = offs[node], end = offs[node + 1];
  float acc[4][8];
#pragma unroll
  for (int kk = 0; kk < 4; ++kk)
#pragma unroll
    for (int j = 0; j < 8; ++j) acc[kk][j] = 0.f;
  for (int i = beg; i < end; ++i) {
    int s = ssrc[i];
    const bf16* hp = Hb + (size_t)s * DD + lk;
#pragma unroll
    for (int kk = 0; kk < 4; ++kk) {
      bf16x8 v = *(const bf16x8*)(hp + kk * 32);
#pragma unroll
      for (int j = 0; j < 8; ++j) acc[kk][j] += (float)v[j];
    }
  }
  float inv = (end > beg) ? 1.0f / (float)(end - beg) : 0.f;
  bf16x8 a2[4];
#pragma unroll
  for (int kk = 0; kk < 4; ++kk)
#pragma unroll
    for (int j = 0; j < 8; ++j) a2[kk][j] = (bf16)(acc[kk][j] * inv);

  // output rows for this lane's C fragment: perm[n0 + 4g + r]
  const int4 p4 = *(const int4*)(perm + n0 + (g << 2));
  const int* prow = (const int*)&p4;

#pragma unroll
  for (int j = 0; j < 8; ++j) {
    int row = j * 16 + lr;
    int rbase = row * 256 + lk * 2;         // byte offset of this lane's chunk
    f32x4 cs = {0.f, 0.f, 0.f, 0.f};
    f32x4 cn = {0.f, 0.f, 0.f, 0.f};
#pragma unroll
    for (int kk = 0; kk < 4; ++kk) {
      int ro = swz(rbase + kk * 64);
      bf16x8 bs = *(const bf16x8*)(smem + ro);
      bf16x8 bn = *(const bf16x8*)(smem + 32768 + ro);
      cs = __builtin_amdgcn_mfma_f32_16x16x32_bf16(a1[kk], bs, cs, 0, 0, 0);
      cn = __builtin_amdgcn_mfma_f32_16x16x32_bf16(a2[kk], bn, cn, 0, 0, 0);
    }
    int col = j * 16 + lr;
    float bb = bias[col];
#pragma unroll
    for (int r = 0; r < 4; ++r) {
      size_t idx = (size_t)prow[r] * DD + col;
      float v = cs[r] + cn[r] + bb;
      if (MODE == 0) H1out[idx] = (bf16)v;
      else           Resb[idx] = (bf16)(Xres[idx] + (float)Hb[idx] + 0.5f * v);
    }
  }
}

// ---- fused attention scores, LDS-staged W_attn --------------------------
// Block = 512 threads (8 waves); Wa staged in 32 KB swizzled LDS.
// view 0 reads res (bf16), view 1 reads v2 (f32).
__global__ __launch_bounds__(512, 4) void k_attn2(const bf16* __restrict__ resb,
                                                  const float* __restrict__ v2f,
                                                  const bf16* __restrict__ Wab,
                                                  const float* __restrict__ bias,
                                                  const float* __restrict__ att,
                                                  float* __restrict__ partial,
                                                  int nbA, int N) {
  __shared__ char smem[32768];   // [128 rows][256 B], swizzled
  __shared__ float smr[8];
  int t = threadIdx.x;
#pragma unroll
  for (int it = 0; it < 4; ++it) {
    int o = (it * 512 + t) * 16;            // linear byte offset in matrix
    *(bf16x8*)(smem + swz(o)) = *(const bf16x8*)(Wab + o / 2);
  }
  __syncthreads();

  int wv = t >> 6;
  int lane = t & 63;
  int gwid = blockIdx.x * 8 + wv;
  int view = gwid & 1;
  int tile = gwid >> 1;
  int n0 = tile << 4;
  float part = 0.f;
  if (n0 < N) {
    int lr = lane & 15;
    int lk = (lane >> 4) << 3;
    bf16x8 a[4];
    if (view) {
      const float* ap = v2f + (size_t)(n0 + lr) * DD + lk;
#pragma unroll
      for (int kk = 0; kk < 4; ++kk) a[kk] = cvt8(ap + kk * 32);
    } else {
      const bf16* ap = resb + (size_t)(n0 + lr) * DD + lk;
#pragma unroll
      for (int kk = 0; kk < 4; ++kk) a[kk] = *(const bf16x8*)(ap + kk * 32);
    }
#pragma unroll
    for (int j = 0; j < 8; ++j) {
      int row = j * 16 + lr;
      int rbase = row * 256 + lk * 2;
      f32x4 c = {0.f, 0.f, 0.f, 0.f};
#pragma unroll
      for (int kk = 0; kk < 4; ++kk) {
        bf16x8 bw = *(const bf16x8*)(smem + swz(rbase + kk * 64));
        c = __builtin_amdgcn_mfma_f32_16x16x32_bf16(a[kk], bw, c, 0, 0, 0);
      }
      int col = j * 16 + lr;
      float aw = att[col], bb = bias[col];
#pragma unroll
      for (int r = 0; r < 4; ++r) part += aw * ftanh(c[r] + bb);
    }
  }
#pragma unroll
  for (int d = 1; d < 64; d <<= 1) part += __shfl_xor(part, d);
  if (lane == 0) smr[wv] = part;
  __syncthreads();
  if (t == 0) {
    partial[blockIdx.x]       = smr[0] + smr[2] + smr[4] + smr[6];  // view 0
    partial[nbA + blockIdx.x] = smr[1] + smr[3] + smr[5] + smr[7];  // view 1
  }
}

// ---- reduce partials -> scores[2] ---------------------------------------
__global__ __launch_bounds__(256) void k_score(const float* __restrict__ partial,
                                               float* __restrict__ scores, int nbA) {
  __shared__ float sm[256];
  int t = threadIdx.x;
#pragma unroll
  for (int v = 0; v < 2; ++v) {
    float s = 0.f;
    for (int i = t; i < nbA; i += 256) s += partial[v * nbA + i];
    sm[t] = s;
    __syncthreads();
#pragma unroll
    for (int d = 128; d > 0; d >>= 1) {
      if (t < d) sm[t] += sm[t + d];
      __syncthreads();
    }
    if (t == 0) scores[v] = sm[0];
    __syncthreads();
  }
}

// ---- final blend: out = b0*res(bf16) + b1*view2(f32) --------------------
__global__ void k_fin(float* __restrict__ out, const bf16* __restrict__ resb,
                      const float* __restrict__ v2,
                      const float* __restrict__ scores, float invN, int total8) {
  int i = blockIdx.x * 256 + threadIdx.x;
  if (i >= total8) return;
  float s0 = scores[0] * invN, s1 = scores[1] * invN;
  float m = fmaxf(s0, s1);
  float e0 = expf(s0 - m), e1 = expf(s1 - m);
  float inv = 1.0f / (e0 + e1);
  float b0 = e0 * inv, b1 = e1 * inv;
  bf16x8 r = ((const bf16x8*)resb)[i];
  f32x4 w0 = ((const f32x4*)v2)[2 * i];
  f32x4 w1 = ((const f32x4*)v2)[2 * i + 1];
  f32x4 o0, o1;
#pragma unroll
  for (int j = 0; j < 4; ++j) {
    o0[j] = b0 * (float)r[j] + b1 * w0[j];
    o1[j] = b0 * (float)r[4 + j] + b1 * w1[j];
  }
  ((f32x4*)out)[2 * i] = o0;
  ((f32x4*)out)[2 * i + 1] = o1;
}

extern "C" void kernel_launch(void* const* d_in, const int* in_sizes, int n_in,
                              void* d_out, int out_size, void* d_ws, size_t ws_size,
                              hipStream_t stream) {
  const float* x   = (const float*)d_in[0];
  const float* v2  = (const float*)d_in[1];
  const float* Wn1 = (const float*)d_in[2];
  const float* Ws1 = (const float*)d_in[3];
  const float* b1  = (const float*)d_in[4];
  const float* Wn2 = (const float*)d_in[5];
  const float* Ws2 = (const float*)d_in[6];
  const float* b2  = (const float*)d_in[7];
  const float* Wa  = (const float*)d_in[8];
  const float* ba  = (const float*)d_in[9];
  const float* att = (const float*)d_in[10];
  const int*  src  = (const int*)d_in[11];
  const int*  dst  = (const int*)d_in[12];
  const int D = in_sizes[4];        // 128
  const int N = in_sizes[0] / D;    // 50000
  const int E = in_sizes[11];       // 640000
  float* out = (float*)d_out;

  char* ws = (char*)d_ws;
  size_t o = 0;
  auto alloc = [&](size_t bytes) -> void* {
    void* p = ws + o;
    o += (bytes + 255) & ~(size_t)255;
    return p;
  };
  int*  cnt    = (int*)alloc((size_t)N * 4);
  int*  offs   = (int*)alloc((size_t)(N + 1) * 4);
  int*  cursor = (int*)alloc((size_t)N * 4);
  int*  ssrc   = (int*)alloc((size_t)E * 4);
  int*  perm   = (int*)alloc((size_t)N * 4);
  int*  dbin   = (int*)alloc(64 * 4);
  int*  dcur   = (int*)alloc(64 * 4);
  bf16* xb     = (bf16*)alloc((size_t)N * D * 2);
  bf16* h1b    = (bf16*)alloc((size_t)N * D * 2);
  bf16* resb   = (bf16*)alloc((size_t)N * D * 2);
  bf16* wb     = (bf16*)alloc((size_t)5 * D * D * 2);
  float* sc    = (float*)alloc(2 * 4);
  int nb = (N + 255) / 256;
  int*  bsum   = (int*)alloc((size_t)nb * 4);

  int tilesPerView = (N + 15) / 16;          // 3125
  int attnWaves = 2 * tilesPerView;          // 6250
  int nbA = (attnWaves + 7) / 8;             // 782 blocks (8 waves each)
  float* apart = (float*)alloc((size_t)2 * nbA * 4);

  // fused prologue
  int nbZ = (N + 255) / 256;                 // zero cnt (+dbin)
  int nbW = (5 * D * D + 255) / 256;         // weights -> bf16
  int nbX = (N * D / 8 + 255) / 256;         // x -> bf16
  k_prep<<<nbZ + nbW + nbX, 256, 0, stream>>>(cnt, dbin, N, Ws1, Wn1, Ws2, Wn2, Wa, wb,
                                              5 * D * D, x, xb, N * D / 8, nbZ, nbW);

  k_hist<<<(E + 255) / 256, 256, 0, stream>>>(dst, cnt, E);
  k_scan1<<<nb, 256, 0, stream>>>(cnt, bsum, N);
  k_scan2<<<1, 256, 0, stream>>>(bsum, nb);
  k_scan3<<<nb, 256, 0, stream>>>(cnt, bsum, offs, cursor, N);
  // degree sort (uses cnt; independent of offs)
  k_dhist<<<nb, 256, 0, stream>>>(cnt, dbin, N);
  k_dscan<<<1, 64, 0, stream>>>(dbin, dcur);
  k_dperm<<<nb, 256, 0, stream>>>(cnt, dcur, perm, N);
  k_scatter<<<(E + 255) / 256, 256, 0, stream>>>(src, dst, cursor, ssrc, E);

  int tiles = (N + 15) / 16;                 // 3125 row tiles
  int layerBlocks = (tiles + 15) / 16;       // 16 tiles (waves) per block

  // layer 1: h1 (bf16) = x@Ws1^T + mean_nb(x)@Wn1^T + b1
  k_layer<0><<<layerBlocks, 1024, 0, stream>>>(xb, offs, ssrc, perm, wb, wb + D * D,
                                               b1, nullptr, h1b, nullptr, N);
  // layer 2: res (bf16) = x + h1 + 0.5*h2
  k_layer<1><<<layerBlocks, 1024, 0, stream>>>(h1b, offs, ssrc, perm, wb + 2 * D * D,
                                               wb + 3 * D * D, b2, x, nullptr, resb, N);
  // fused attention scores over [res, view2], W_attn LDS-staged
  k_attn2<<<nbA, 512, 0, stream>>>(resb, v2, wb + 4 * D * D, ba, att, apart, nbA, N);
  k_score<<<1, 256, 0, stream>>>(apart, sc, nbA);
  // final blend
  k_fin<<<((N * D / 8) + 255) / 256, 256, 0, stream>>>(out, resb, v2, sc,
                                                       1.0f / (float)N, N * D / 8);
}

// Round 13
// 287.103 us; speedup vs baseline: 1.8617x; 1.8617x over previous
//
#include <hip/hip_runtime.h>

#define DD 128

using bf16 = __bf16;
typedef __bf16 bf16x8 __attribute__((ext_vector_type(8)));
typedef float f32x4 __attribute__((ext_vector_type(4)));

__device__ inline bf16x8 cvt8(const float* p) {
  f32x4 v0 = *(const f32x4*)p;
  f32x4 v1 = *(const f32x4*)(p + 4);
  bf16x8 r;
  r[0] = (bf16)v0[0]; r[1] = (bf16)v0[1]; r[2] = (bf16)v0[2]; r[3] = (bf16)v0[3];
  r[4] = (bf16)v1[0]; r[5] = (bf16)v1[1]; r[6] = (bf16)v1[2]; r[7] = (bf16)v1[3];
  return r;
}

// fast tanh: 1 - 2/(e^{2x}+1); v_exp + v_rcp, saturates correctly at +-1
__device__ inline float ftanh(float x) {
  float e2 = __expf(2.0f * x);
  return 1.0f - 2.0f * __builtin_amdgcn_rcpf(e2 + 1.0f);
}

// XOR swizzle for [128 rows][256 B] LDS tiles (G4)
__device__ inline int swz(int o) { return o ^ (((o >> 8) & 7) << 4); }

// ---- fused prologue: zero cnt | weights->bf16 | x->bf16 ------------------
__global__ void k_prep(int* __restrict__ cnt, int N,
                       const float* __restrict__ w0, const float* __restrict__ w1,
                       const float* __restrict__ w2, const float* __restrict__ w3,
                       const float* __restrict__ w4, bf16* __restrict__ wb, int totalW,
                       const float* __restrict__ x, bf16* __restrict__ xb, int total8,
                       int nbZ, int nbW) {
  int b = blockIdx.x;
  if (b < nbZ) {
    int i = b * 256 + threadIdx.x;
    if (i < N) cnt[i] = 0;
  } else if (b < nbZ + nbW) {
    int i = (b - nbZ) * 256 + threadIdx.x;
    if (i < totalW) {
      int m = i >> 14;           // DD*DD = 16384
      int r = i & 16383;
      const float* s = m == 0 ? w0 : m == 1 ? w1 : m == 2 ? w2 : m == 3 ? w3 : w4;
      wb[i] = (bf16)s[r];
    }
  } else {
    int i = (b - nbZ - nbW) * 256 + threadIdx.x;
    if (i < total8) *(bf16x8*)(xb + (size_t)i * 8) = cvt8(x + (size_t)i * 8);
  }
}

// ---- CSR build ----------------------------------------------------------
__global__ void k_hist(const int* __restrict__ dst, int* __restrict__ cnt, int E) {
  int e = blockIdx.x * 256 + threadIdx.x;
  if (e < E) atomicAdd(&cnt[dst[e]], 1);
}

__global__ __launch_bounds__(256) void k_scan1(const int* __restrict__ cnt,
                                               int* __restrict__ bsum, int N) {
  __shared__ int sm[256];
  int t = threadIdx.x;
  int i = blockIdx.x * 256 + t;
  sm[t] = (i < N) ? cnt[i] : 0;
  __syncthreads();
#pragma unroll
  for (int d = 128; d > 0; d >>= 1) {
    if (t < d) sm[t] += sm[t + d];
    __syncthreads();
  }
  if (t == 0) bsum[blockIdx.x] = sm[0];
}

__global__ __launch_bounds__(256) void k_scan2(int* __restrict__ bsum, int nb) {
  __shared__ int sm[256];
  int t = threadIdx.x;
  int v = (t < nb) ? bsum[t] : 0;
  sm[t] = v;
  __syncthreads();
#pragma unroll
  for (int d = 1; d < 256; d <<= 1) {
    int u = (t >= d) ? sm[t - d] : 0;
    __syncthreads();
    sm[t] += u;
    __syncthreads();
  }
  if (t < nb) bsum[t] = sm[t] - v;   // exclusive prefix
}

__global__ __launch_bounds__(256) void k_scan3(const int* __restrict__ cnt,
                                               const int* __restrict__ bsum,
                                               int* __restrict__ offs,
                                               int* __restrict__ cursor, int N) {
  __shared__ int sm[256];
  int t = threadIdx.x;
  int i = blockIdx.x * 256 + t;
  int v = (i < N) ? cnt[i] : 0;
  sm[t] = v;
  __syncthreads();
#pragma unroll
  for (int d = 1; d < 256; d <<= 1) {
    int u = (t >= d) ? sm[t - d] : 0;
    __syncthreads();
    sm[t] += u;
    __syncthreads();
  }
  int incl = sm[t];
  int base = bsum[blockIdx.x];
  if (i < N) {
    int ex = base + incl - v;
    offs[i] = ex;
    cursor[i] = ex;
    if (i == N - 1) offs[N] = base + incl;
  }
}

__global__ void k_scatter(const int* __restrict__ src, const int* __restrict__ dst,
                          int* __restrict__ cursor, int* __restrict__ ssrc, int E) {
  int e = blockIdx.x * 256 + threadIdx.x;
  if (e < E) {
    int d = dst[e];
    int p = atomicAdd(&cursor[d], 1);
    ssrc[p] = src[e];
  }
}

// ---- degree sort: contention-free two-level counting sort ---------------
// (R12's 64-address global atomics cost ~150us/kernel; LDS hist fixes it.)
__global__ __launch_bounds__(256) void k_dhist(const int* __restrict__ cnt,
                                               int* __restrict__ bhist, int N) {
  __shared__ int h[64];
  int t = threadIdx.x;
  if (t < 64) h[t] = 0;
  __syncthreads();
  int i = blockIdx.x * 256 + t;
  if (i < N) atomicAdd(&h[min(cnt[i], 63)], 1);     // LDS atomic
  __syncthreads();
  if (t < 64) bhist[blockIdx.x * 64 + t] = h[t];
}

// one block: per-bin exclusive prefix across blocks + descending-bin base
__global__ __launch_bounds__(64) void k_dscan(int* __restrict__ bhist, int NB) {
  __shared__ int tot[64];
  int t = threadIdx.x;
  int run = 0;
  for (int b = 0; b < NB; ++b) {
    int v = bhist[b * 64 + t];
    bhist[b * 64 + t] = run;
    run += v;
  }
  tot[t] = run;
  __syncthreads();
  int base = 0;
  for (int b2 = t + 1; b2 < 64; ++b2) base += tot[b2];  // heavy bins first
  for (int b = 0; b < NB; ++b) bhist[b * 64 + t] += base;
}

__global__ __launch_bounds__(256) void k_dperm(const int* __restrict__ cnt,
                                               const int* __restrict__ bhist,
                                               int* __restrict__ perm, int N) {
  __shared__ int h[64];
  int t = threadIdx.x;
  if (t < 64) h[t] = 0;
  __syncthreads();
  int i = blockIdx.x * 256 + t;
  if (i < N) {
    int bin = min(cnt[i], 63);
    int local = atomicAdd(&h[bin], 1);                // LDS atomic
    perm[bhist[blockIdx.x * 64 + bin] + local] = i;
  }
}

// ---- fused SAGE layer: aggregate + GEMM, degree-sorted ------------------
// Block = 1024 threads (16 waves), Ws+Wn staged in 64 KB swizzled LDS.
// Wave w handles nodes perm[tile*16 .. tile*16+15] (degree-homogeneous).
// MODE 0: H1out[perm-row] = (bf16)v
// MODE 1: Resb[perm-row] = (bf16)(Xres + h1 + 0.5*v)   (res, bf16)
template <int MODE>
__global__ __launch_bounds__(1024, 1) void k_layer(const bf16* __restrict__ Hb,
                                                   const int* __restrict__ offs,
                                                   const int* __restrict__ ssrc,
                                                   const int* __restrict__ perm,
                                                   const bf16* __restrict__ Wsb,
                                                   const bf16* __restrict__ Wnb,
                                                   const float* __restrict__ bias,
                                                   const float* __restrict__ Xres,
                                                   bf16* __restrict__ H1out,
                                                   bf16* __restrict__ Resb, int N) {
  __shared__ char smem[65536];   // [2][128 rows][256 B], swizzled
  int t = threadIdx.x;
#pragma unroll
  for (int m = 0; m < 2; ++m) {
    const bf16* wsrc = m ? Wnb : Wsb;
#pragma unroll
    for (int it = 0; it < 2; ++it) {
      int o = (it * 1024 + t) * 16;         // linear byte offset in matrix
      *(bf16x8*)(smem + m * 32768 + swz(o)) = *(const bf16x8*)(wsrc + o / 2);
    }
  }
  __syncthreads();

  int wv = t >> 6;
  int lane = t & 63;
  int tile = blockIdx.x * 16 + wv;
  int n0 = tile << 4;
  if (n0 >= N) return;
  int lr = lane & 15;
  int g = lane >> 4;
  int lk = g << 3;                          // k offset in elems (8-elem chunk)

  int node = perm[n0 + lr];                 // degree-sorted node id

  // A1 (self) fragments
  const bf16* a1p = Hb + (size_t)node * DD + lk;
  bf16x8 a1[4];
#pragma unroll
  for (int kk = 0; kk < 4; ++kk) a1[kk] = *(const bf16x8*)(a1p + kk * 32);

  // aggregate neighbor mean into A2 fragments (f32 acc)
  int beg = offs[node], end = offs[node + 1];
  float acc[4][8];
#pragma unroll
  for (int kk = 0; kk < 4; ++kk)
#pragma unroll
    for (int j = 0; j < 8; ++j) acc[kk][j] = 0.f;
  for (int i = beg; i < end; ++i) {
    int s = ssrc[i];
    const bf16* hp = Hb + (size_t)s * DD + lk;
#pragma unroll
    for (int kk = 0; kk < 4; ++kk) {
      bf16x8 v = *(const bf16x8*)(hp + kk * 32);
#pragma unroll
      for (int j = 0; j < 8; ++j) acc[kk][j] += (float)v[j];
    }
  }
  float inv = (end > beg) ? 1.0f / (float)(end - beg) : 0.f;
  bf16x8 a2[4];
#pragma unroll
  for (int kk = 0; kk < 4; ++kk)
#pragma unroll
    for (int j = 0; j < 8; ++j) a2[kk][j] = (bf16)(acc[kk][j] * inv);

  // output rows for this lane's C fragment: perm[n0 + 4g + r]
  const int4 p4 = *(const int4*)(perm + n0 + (g << 2));
  const int* prow = (const int*)&p4;

#pragma unroll
  for (int j = 0; j < 8; ++j) {
    int row = j * 16 + lr;
    int rbase = row * 256 + lk * 2;         // byte offset of this lane's chunk
    f32x4 cs = {0.f, 0.f, 0.f, 0.f};
    f32x4 cn = {0.f, 0.f, 0.f, 0.f};
#pragma unroll
    for (int kk = 0; kk < 4; ++kk) {
      int ro = swz(rbase + kk * 64);
      bf16x8 bs = *(const bf16x8*)(smem + ro);
      bf16x8 bn = *(const bf16x8*)(smem + 32768 + ro);
      cs = __builtin_amdgcn_mfma_f32_16x16x32_bf16(a1[kk], bs, cs, 0, 0, 0);
      cn = __builtin_amdgcn_mfma_f32_16x16x32_bf16(a2[kk], bn, cn, 0, 0, 0);
    }
    int col = j * 16 + lr;
    float bb = bias[col];
#pragma unroll
    for (int r = 0; r < 4; ++r) {
      size_t idx = (size_t)prow[r] * DD + col;
      float v = cs[r] + cn[r] + bb;
      if (MODE == 0) H1out[idx] = (bf16)v;
      else           Resb[idx] = (bf16)(Xres[idx] + (float)Hb[idx] + 0.5f * v);
    }
  }
}

// ---- fused attention scores, LDS-staged W_attn --------------------------
// Block = 512 threads (8 waves); Wa staged in 32 KB swizzled LDS.
// view 0 reads res (bf16), view 1 reads v2 (f32).
__global__ __launch_bounds__(512, 4) void k_attn2(const bf16* __restrict__ resb,
                                                  const float* __restrict__ v2f,
                                                  const bf16* __restrict__ Wab,
                                                  const float* __restrict__ bias,
                                                  const float* __restrict__ att,
                                                  float* __restrict__ partial,
                                                  int nbA, int N) {
  __shared__ char smem[32768];   // [128 rows][256 B], swizzled
  __shared__ float smr[8];
  int t = threadIdx.x;
#pragma unroll
  for (int it = 0; it < 4; ++it) {
    int o = (it * 512 + t) * 16;            // linear byte offset in matrix
    *(bf16x8*)(smem + swz(o)) = *(const bf16x8*)(Wab + o / 2);
  }
  __syncthreads();

  int wv = t >> 6;
  int lane = t & 63;
  int gwid = blockIdx.x * 8 + wv;
  int view = gwid & 1;
  int tile = gwid >> 1;
  int n0 = tile << 4;
  float part = 0.f;
  if (n0 < N) {
    int lr = lane & 15;
    int lk = (lane >> 4) << 3;
    bf16x8 a[4];
    if (view) {
      const float* ap = v2f + (size_t)(n0 + lr) * DD + lk;
#pragma unroll
      for (int kk = 0; kk < 4; ++kk) a[kk] = cvt8(ap + kk * 32);
    } else {
      const bf16* ap = resb + (size_t)(n0 + lr) * DD + lk;
#pragma unroll
      for (int kk = 0; kk < 4; ++kk) a[kk] = *(const bf16x8*)(ap + kk * 32);
    }
#pragma unroll
    for (int j = 0; j < 8; ++j) {
      int row = j * 16 + lr;
      int rbase = row * 256 + lk * 2;
      f32x4 c = {0.f, 0.f, 0.f, 0.f};
#pragma unroll
      for (int kk = 0; kk < 4; ++kk) {
        bf16x8 bw = *(const bf16x8*)(smem + swz(rbase + kk * 64));
        c = __builtin_amdgcn_mfma_f32_16x16x32_bf16(a[kk], bw, c, 0, 0, 0);
      }
      int col = j * 16 + lr;
      float aw = att[col], bb = bias[col];
#pragma unroll
      for (int r = 0; r < 4; ++r) part += aw * ftanh(c[r] + bb);
    }
  }
#pragma unroll
  for (int d = 1; d < 64; d <<= 1) part += __shfl_xor(part, d);
  if (lane == 0) smr[wv] = part;
  __syncthreads();
  if (t == 0) {
    partial[blockIdx.x]       = smr[0] + smr[2] + smr[4] + smr[6];  // view 0
    partial[nbA + blockIdx.x] = smr[1] + smr[3] + smr[5] + smr[7];  // view 1
  }
}

// ---- reduce partials -> scores[2] ---------------------------------------
__global__ __launch_bounds__(256) void k_score(const float* __restrict__ partial,
                                               float* __restrict__ scores, int nbA) {
  __shared__ float sm[256];
  int t = threadIdx.x;
#pragma unroll
  for (int v = 0; v < 2; ++v) {
    float s = 0.f;
    for (int i = t; i < nbA; i += 256) s += partial[v * nbA + i];
    sm[t] = s;
    __syncthreads();
#pragma unroll
    for (int d = 128; d > 0; d >>= 1) {
      if (t < d) sm[t] += sm[t + d];
      __syncthreads();
    }
    if (t == 0) scores[v] = sm[0];
    __syncthreads();
  }
}

// ---- final blend: out = b0*res(bf16) + b1*view2(f32) --------------------
__global__ void k_fin(float* __restrict__ out, const bf16* __restrict__ resb,
                      const float* __restrict__ v2,
                      const float* __restrict__ scores, float invN, int total8) {
  int i = blockIdx.x * 256 + threadIdx.x;
  if (i >= total8) return;
  float s0 = scores[0] * invN, s1 = scores[1] * invN;
  float m = fmaxf(s0, s1);
  float e0 = expf(s0 - m), e1 = expf(s1 - m);
  float inv = 1.0f / (e0 + e1);
  float b0 = e0 * inv, b1 = e1 * inv;
  bf16x8 r = ((const bf16x8*)resb)[i];
  f32x4 w0 = ((const f32x4*)v2)[2 * i];
  f32x4 w1 = ((const f32x4*)v2)[2 * i + 1];
  f32x4 o0, o1;
#pragma unroll
  for (int j = 0; j < 4; ++j) {
    o0[j] = b0 * (float)r[j] + b1 * w0[j];
    o1[j] = b0 * (float)r[4 + j] + b1 * w1[j];
  }
  ((f32x4*)out)[2 * i] = o0;
  ((f32x4*)out)[2 * i + 1] = o1;
}

extern "C" void kernel_launch(void* const* d_in, const int* in_sizes, int n_in,
                              void* d_out, int out_size, void* d_ws, size_t ws_size,
                              hipStream_t stream) {
  const float* x   = (const float*)d_in[0];
  const float* v2  = (const float*)d_in[1];
  const float* Wn1 = (const float*)d_in[2];
  const float* Ws1 = (const float*)d_in[3];
  const float* b1  = (const float*)d_in[4];
  const float* Wn2 = (const float*)d_in[5];
  const float* Ws2 = (const float*)d_in[6];
  const float* b2  = (const float*)d_in[7];
  const float* Wa  = (const float*)d_in[8];
  const float* ba  = (const float*)d_in[9];
  const float* att = (const float*)d_in[10];
  const int*  src  = (const int*)d_in[11];
  const int*  dst  = (const int*)d_in[12];
  const int D = in_sizes[4];        // 128
  const int N = in_sizes[0] / D;    // 50000
  const int E = in_sizes[11];       // 640000
  float* out = (float*)d_out;

  char* ws = (char*)d_ws;
  size_t o = 0;
  auto alloc = [&](size_t bytes) -> void* {
    void* p = ws + o;
    o += (bytes + 255) & ~(size_t)255;
    return p;
  };
  int*  cnt    = (int*)alloc((size_t)N * 4);
  int*  offs   = (int*)alloc((size_t)(N + 1) * 4);
  int*  cursor = (int*)alloc((size_t)N * 4);
  int*  ssrc   = (int*)alloc((size_t)E * 4);
  int*  perm   = (int*)alloc((size_t)N * 4);
  bf16* xb     = (bf16*)alloc((size_t)N * D * 2);
  bf16* h1b    = (bf16*)alloc((size_t)N * D * 2);
  bf16* resb   = (bf16*)alloc((size_t)N * D * 2);
  bf16* wb     = (bf16*)alloc((size_t)5 * D * D * 2);
  float* sc    = (float*)alloc(2 * 4);
  int nb = (N + 255) / 256;
  int*  bsum   = (int*)alloc((size_t)nb * 4);
  int*  bhist  = (int*)alloc((size_t)nb * 64 * 4);

  int tilesPerView = (N + 15) / 16;          // 3125
  int attnWaves = 2 * tilesPerView;          // 6250
  int nbA = (attnWaves + 7) / 8;             // 782 blocks (8 waves each)
  float* apart = (float*)alloc((size_t)2 * nbA * 4);

  // fused prologue
  int nbZ = (N + 255) / 256;                 // zero cnt
  int nbW = (5 * D * D + 255) / 256;         // weights -> bf16
  int nbX = (N * D / 8 + 255) / 256;         // x -> bf16
  k_prep<<<nbZ + nbW + nbX, 256, 0, stream>>>(cnt, N, Ws1, Wn1, Ws2, Wn2, Wa, wb,
                                              5 * D * D, x, xb, N * D / 8, nbZ, nbW);

  k_hist<<<(E + 255) / 256, 256, 0, stream>>>(dst, cnt, E);
  k_scan1<<<nb, 256, 0, stream>>>(cnt, bsum, N);
  k_scan2<<<1, 256, 0, stream>>>(bsum, nb);
  k_scan3<<<nb, 256, 0, stream>>>(cnt, bsum, offs, cursor, N);
  // degree sort (contention-free: LDS hist + block-local ranks)
  k_dhist<<<nb, 256, 0, stream>>>(cnt, bhist, N);
  k_dscan<<<1, 64, 0, stream>>>(bhist, nb);
  k_dperm<<<nb, 256, 0, stream>>>(cnt, bhist, perm, N);
  k_scatter<<<(E + 255) / 256, 256, 0, stream>>>(src, dst, cursor, ssrc, E);

  int tiles = (N + 15) / 16;                 // 3125 row tiles
  int layerBlocks = (tiles + 15) / 16;       // 16 tiles (waves) per block

  // layer 1: h1 (bf16) = x@Ws1^T + mean_nb(x)@Wn1^T + b1
  k_layer<0><<<layerBlocks, 1024, 0, stream>>>(xb, offs, ssrc, perm, wb, wb + D * D,
                                               b1, nullptr, h1b, nullptr, N);
  // layer 2: res (bf16) = x + h1 + 0.5*h2
  k_layer<1><<<layerBlocks, 1024, 0, stream>>>(h1b, offs, ssrc, perm, wb + 2 * D * D,
                                               wb + 3 * D * D, b2, x, nullptr, resb, N);
  // fused attention scores over [res, view2], W_attn LDS-staged
  k_attn2<<<nbA, 512, 0, stream>>>(resb, v2, wb + 4 * D * D, ba, att, apart, nbA, N);
  k_score<<<1, 256, 0, stream>>>(apart, sc, nbA);
  // final blend
  k_fin<<<((N * D / 8) + 255) / 256, 256, 0, stream>>>(out, resb, v2, sc,
                                                       1.0f / (float)N, N * D / 8);
}

// Round 14
// 258.393 us; speedup vs baseline: 2.0686x; 1.1111x over previous
//
#include <hip/hip_runtime.h>

#define DD 128

using bf16 = __bf16;
typedef __bf16 bf16x8 __attribute__((ext_vector_type(8)));
typedef float f32x4 __attribute__((ext_vector_type(4)));

__device__ inline bf16x8 cvt8(const float* p) {
  f32x4 v0 = *(const f32x4*)p;
  f32x4 v1 = *(const f32x4*)(p + 4);
  bf16x8 r;
  r[0] = (bf16)v0[0]; r[1] = (bf16)v0[1]; r[2] = (bf16)v0[2]; r[3] = (bf16)v0[3];
  r[4] = (bf16)v1[0]; r[5] = (bf16)v1[1]; r[6] = (bf16)v1[2]; r[7] = (bf16)v1[3];
  return r;
}

// fast tanh: 1 - 2/(e^{2x}+1); v_exp + v_rcp, saturates correctly at +-1
__device__ inline float ftanh(float x) {
  float e2 = __expf(2.0f * x);
  return 1.0f - 2.0f * __builtin_amdgcn_rcpf(e2 + 1.0f);
}

// XOR swizzle for [128 rows][256 B] LDS tiles (G4)
__device__ inline int swz(int o) { return o ^ (((o >> 8) & 7) << 4); }

// ---- fused prologue: zero cnt | weights->bf16 | x->bf16 ------------------
__global__ void k_prep(int* __restrict__ cnt, int N,
                       const float* __restrict__ w0, const float* __restrict__ w1,
                       const float* __restrict__ w2, const float* __restrict__ w3,
                       const float* __restrict__ w4, bf16* __restrict__ wb, int totalW,
                       const float* __restrict__ x, bf16* __restrict__ xb, int total8,
                       int nbZ, int nbW) {
  int b = blockIdx.x;
  if (b < nbZ) {
    int i = b * 256 + threadIdx.x;
    if (i < N) cnt[i] = 0;
  } else if (b < nbZ + nbW) {
    int i = (b - nbZ) * 256 + threadIdx.x;
    if (i < totalW) {
      int m = i >> 14;           // DD*DD = 16384
      int r = i & 16383;
      const float* s = m == 0 ? w0 : m == 1 ? w1 : m == 2 ? w2 : m == 3 ? w3 : w4;
      wb[i] = (bf16)s[r];
    }
  } else {
    int i = (b - nbZ - nbW) * 256 + threadIdx.x;
    if (i < total8) *(bf16x8*)(xb + (size_t)i * 8) = cvt8(x + (size_t)i * 8);
  }
}

// ---- CSR build ----------------------------------------------------------
__global__ void k_hist(const int* __restrict__ dst, int* __restrict__ cnt, int E) {
  int e = blockIdx.x * 256 + threadIdx.x;
  if (e < E) atomicAdd(&cnt[dst[e]], 1);
}

__global__ __launch_bounds__(256) void k_scan1(const int* __restrict__ cnt,
                                               int* __restrict__ bsum, int N) {
  __shared__ int sm[256];
  int t = threadIdx.x;
  int i = blockIdx.x * 256 + t;
  sm[t] = (i < N) ? cnt[i] : 0;
  __syncthreads();
#pragma unroll
  for (int d = 128; d > 0; d >>= 1) {
    if (t < d) sm[t] += sm[t + d];
    __syncthreads();
  }
  if (t == 0) bsum[blockIdx.x] = sm[0];
}

__global__ __launch_bounds__(256) void k_scan2(int* __restrict__ bsum, int nb) {
  __shared__ int sm[256];
  int t = threadIdx.x;
  int v = (t < nb) ? bsum[t] : 0;
  sm[t] = v;
  __syncthreads();
#pragma unroll
  for (int d = 1; d < 256; d <<= 1) {
    int u = (t >= d) ? sm[t - d] : 0;
    __syncthreads();
    sm[t] += u;
    __syncthreads();
  }
  if (t < nb) bsum[t] = sm[t] - v;   // exclusive prefix
}

__global__ __launch_bounds__(256) void k_scan3(const int* __restrict__ cnt,
                                               const int* __restrict__ bsum,
                                               int* __restrict__ offs,
                                               int* __restrict__ cursor, int N) {
  __shared__ int sm[256];
  int t = threadIdx.x;
  int i = blockIdx.x * 256 + t;
  int v = (i < N) ? cnt[i] : 0;
  sm[t] = v;
  __syncthreads();
#pragma unroll
  for (int d = 1; d < 256; d <<= 1) {
    int u = (t >= d) ? sm[t - d] : 0;
    __syncthreads();
    sm[t] += u;
    __syncthreads();
  }
  int incl = sm[t];
  int base = bsum[blockIdx.x];
  if (i < N) {
    int ex = base + incl - v;
    offs[i] = ex;
    cursor[i] = ex;
    if (i == N - 1) offs[N] = base + incl;
  }
}

__global__ void k_scatter(const int* __restrict__ src, const int* __restrict__ dst,
                          int* __restrict__ cursor, int* __restrict__ ssrc, int E) {
  int e = blockIdx.x * 256 + threadIdx.x;
  if (e < E) {
    int d = dst[e];
    int p = atomicAdd(&cursor[d], 1);
    ssrc[p] = src[e];
  }
}

// ---- degree sort: contention-free two-level counting sort ---------------
__global__ __launch_bounds__(256) void k_dhist(const int* __restrict__ cnt,
                                               int* __restrict__ bhist, int N) {
  __shared__ int h[64];
  int t = threadIdx.x;
  if (t < 64) h[t] = 0;
  __syncthreads();
  int i = blockIdx.x * 256 + t;
  if (i < N) atomicAdd(&h[min(cnt[i], 63)], 1);     // LDS atomic
  __syncthreads();
  if (t < 64) bhist[blockIdx.x * 64 + t] = h[t];
}

// one block: per-bin exclusive prefix across blocks + descending-bin base
__global__ __launch_bounds__(64) void k_dscan(int* __restrict__ bhist, int NB) {
  __shared__ int tot[64];
  int t = threadIdx.x;
  int run = 0;
  for (int b = 0; b < NB; ++b) {
    int v = bhist[b * 64 + t];
    bhist[b * 64 + t] = run;
    run += v;
  }
  tot[t] = run;
  __syncthreads();
  int base = 0;
  for (int b2 = t + 1; b2 < 64; ++b2) base += tot[b2];  // heavy bins first
  for (int b = 0; b < NB; ++b) bhist[b * 64 + t] += base;
}

__global__ __launch_bounds__(256) void k_dperm(const int* __restrict__ cnt,
                                               const int* __restrict__ bhist,
                                               int* __restrict__ perm, int N) {
  __shared__ int h[64];
  int t = threadIdx.x;
  if (t < 64) h[t] = 0;
  __syncthreads();
  int i = blockIdx.x * 256 + t;
  if (i < N) {
    int bin = min(cnt[i], 63);
    int local = atomicAdd(&h[bin], 1);                // LDS atomic
    perm[bhist[blockIdx.x * 64 + bin] + local] = i;
  }
}

// ---- fused SAGE layer: aggregate + GEMM, degree-sorted + load-balanced --
// Block = 1024 threads (16 waves), Ws+Wn staged in 64 KB swizzled LDS.
// Wave wv of block b handles tile = wv*gridDim + b: waves stay degree-
// homogeneous (16 consecutive perm entries) while each block samples all
// degree strata (fixes R13's inter-block imbalance).
// MODE 0: H1out[perm-row] = (bf16)v
// MODE 1: Resb[perm-row] = (bf16)(Xres + h1 + 0.5*v)   (res, bf16)
template <int MODE>
__global__ __launch_bounds__(1024, 1) void k_layer(const bf16* __restrict__ Hb,
                                                   const int* __restrict__ offs,
                                                   const int* __restrict__ ssrc,
                                                   const int* __restrict__ perm,
                                                   const bf16* __restrict__ Wsb,
                                                   const bf16* __restrict__ Wnb,
                                                   const float* __restrict__ bias,
                                                   const float* __restrict__ Xres,
                                                   bf16* __restrict__ H1out,
                                                   bf16* __restrict__ Resb, int N) {
  __shared__ char smem[65536];   // [2][128 rows][256 B], swizzled
  int t = threadIdx.x;
#pragma unroll
  for (int m = 0; m < 2; ++m) {
    const bf16* wsrc = m ? Wnb : Wsb;
#pragma unroll
    for (int it = 0; it < 2; ++it) {
      int o = (it * 1024 + t) * 16;         // linear byte offset in matrix
      *(bf16x8*)(smem + m * 32768 + swz(o)) = *(const bf16x8*)(wsrc + o / 2);
    }
  }
  __syncthreads();

  int wv = t >> 6;
  int lane = t & 63;
  int tile = wv * gridDim.x + blockIdx.x;   // stride-interleaved (balance)
  int n0 = tile << 4;
  if (n0 >= N) return;
  int lr = lane & 15;
  int g = lane >> 4;
  int lk = g << 3;                          // k offset in elems (8-elem chunk)

  int node = perm[n0 + lr];                 // degree-sorted node id

  // A1 (self) fragments
  const bf16* a1p = Hb + (size_t)node * DD + lk;
  bf16x8 a1[4];
#pragma unroll
  for (int kk = 0; kk < 4; ++kk) a1[kk] = *(const bf16x8*)(a1p + kk * 32);

  // aggregate neighbor mean into A2 fragments (f32 acc)
  int beg = offs[node], end = offs[node + 1];
  float acc[4][8];
#pragma unroll
  for (int kk = 0; kk < 4; ++kk)
#pragma unroll
    for (int j = 0; j < 8; ++j) acc[kk][j] = 0.f;
  for (int i = beg; i < end; ++i) {
    int s = ssrc[i];
    const bf16* hp = Hb + (size_t)s * DD + lk;
#pragma unroll
    for (int kk = 0; kk < 4; ++kk) {
      bf16x8 v = *(const bf16x8*)(hp + kk * 32);
#pragma unroll
      for (int j = 0; j < 8; ++j) acc[kk][j] += (float)v[j];
    }
  }
  float inv = (end > beg) ? 1.0f / (float)(end - beg) : 0.f;
  bf16x8 a2[4];
#pragma unroll
  for (int kk = 0; kk < 4; ++kk)
#pragma unroll
    for (int j = 0; j < 8; ++j) a2[kk][j] = (bf16)(acc[kk][j] * inv);

  // output rows for this lane's C fragment: perm[n0 + 4g + r]
  const int4 p4 = *(const int4*)(perm + n0 + (g << 2));
  const int* prow = (const int*)&p4;

#pragma unroll
  for (int j = 0; j < 8; ++j) {
    int row = j * 16 + lr;
    int rbase = row * 256 + lk * 2;         // byte offset of this lane's chunk
    f32x4 cs = {0.f, 0.f, 0.f, 0.f};
    f32x4 cn = {0.f, 0.f, 0.f, 0.f};
#pragma unroll
    for (int kk = 0; kk < 4; ++kk) {
      int ro = swz(rbase + kk * 64);
      bf16x8 bs = *(const bf16x8*)(smem + ro);
      bf16x8 bn = *(const bf16x8*)(smem + 32768 + ro);
      cs = __builtin_amdgcn_mfma_f32_16x16x32_bf16(a1[kk], bs, cs, 0, 0, 0);
      cn = __builtin_amdgcn_mfma_f32_16x16x32_bf16(a2[kk], bn, cn, 0, 0, 0);
    }
    int col = j * 16 + lr;
    float bb = bias[col];
#pragma unroll
    for (int r = 0; r < 4; ++r) {
      size_t idx = (size_t)prow[r] * DD + col;
      float v = cs[r] + cn[r] + bb;
      if (MODE == 0) H1out[idx] = (bf16)v;
      else           Resb[idx] = (bf16)(Xres[idx] + (float)Hb[idx] + 0.5f * v);
    }
  }
}

// ---- fused attention scores, LDS-staged W_attn --------------------------
// Block = 512 threads (8 waves); Wa staged in 32 KB swizzled LDS.
// view 0 reads res (bf16), view 1 reads v2 (f32).
__global__ __launch_bounds__(512, 4) void k_attn2(const bf16* __restrict__ resb,
                                                  const float* __restrict__ v2f,
                                                  const bf16* __restrict__ Wab,
                                                  const float* __restrict__ bias,
                                                  const float* __restrict__ att,
                                                  float* __restrict__ partial,
                                                  int nbA, int N) {
  __shared__ char smem[32768];   // [128 rows][256 B], swizzled
  __shared__ float smr[8];
  int t = threadIdx.x;
#pragma unroll
  for (int it = 0; it < 4; ++it) {
    int o = (it * 512 + t) * 16;            // linear byte offset in matrix
    *(bf16x8*)(smem + swz(o)) = *(const bf16x8*)(Wab + o / 2);
  }
  __syncthreads();

  int wv = t >> 6;
  int lane = t & 63;
  int gwid = blockIdx.x * 8 + wv;
  int view = gwid & 1;
  int tile = gwid >> 1;
  int n0 = tile << 4;
  float part = 0.f;
  if (n0 < N) {
    int lr = lane & 15;
    int lk = (lane >> 4) << 3;
    bf16x8 a[4];
    if (view) {
      const float* ap = v2f + (size_t)(n0 + lr) * DD + lk;
#pragma unroll
      for (int kk = 0; kk < 4; ++kk) a[kk] = cvt8(ap + kk * 32);
    } else {
      const bf16* ap = resb + (size_t)(n0 + lr) * DD + lk;
#pragma unroll
      for (int kk = 0; kk < 4; ++kk) a[kk] = *(const bf16x8*)(ap + kk * 32);
    }
#pragma unroll
    for (int j = 0; j < 8; ++j) {
      int row = j * 16 + lr;
      int rbase = row * 256 + lk * 2;
      f32x4 c = {0.f, 0.f, 0.f, 0.f};
#pragma unroll
      for (int kk = 0; kk < 4; ++kk) {
        bf16x8 bw = *(const bf16x8*)(smem + swz(rbase + kk * 64));
        c = __builtin_amdgcn_mfma_f32_16x16x32_bf16(a[kk], bw, c, 0, 0, 0);
      }
      int col = j * 16 + lr;
      float aw = att[col], bb = bias[col];
#pragma unroll
      for (int r = 0; r < 4; ++r) part += aw * ftanh(c[r] + bb);
    }
  }
#pragma unroll
  for (int d = 1; d < 64; d <<= 1) part += __shfl_xor(part, d);
  if (lane == 0) smr[wv] = part;
  __syncthreads();
  if (t == 0) {
    partial[blockIdx.x]       = smr[0] + smr[2] + smr[4] + smr[6];  // view 0
    partial[nbA + blockIdx.x] = smr[1] + smr[3] + smr[5] + smr[7];  // view 1
  }
}

// ---- reduce partials -> scores[2] ---------------------------------------
__global__ __launch_bounds__(256) void k_score(const float* __restrict__ partial,
                                               float* __restrict__ scores, int nbA) {
  __shared__ float sm[256];
  int t = threadIdx.x;
#pragma unroll
  for (int v = 0; v < 2; ++v) {
    float s = 0.f;
    for (int i = t; i < nbA; i += 256) s += partial[v * nbA + i];
    sm[t] = s;
    __syncthreads();
#pragma unroll
    for (int d = 128; d > 0; d >>= 1) {
      if (t < d) sm[t] += sm[t + d];
      __syncthreads();
    }
    if (t == 0) scores[v] = sm[0];
    __syncthreads();
  }
}

// ---- final blend: out = b0*res(bf16) + b1*view2(f32) --------------------
__global__ void k_fin(float* __restrict__ out, const bf16* __restrict__ resb,
                      const float* __restrict__ v2,
                      const float* __restrict__ scores, float invN, int total8) {
  int i = blockIdx.x * 256 + threadIdx.x;
  if (i >= total8) return;
  float s0 = scores[0] * invN, s1 = scores[1] * invN;
  float m = fmaxf(s0, s1);
  float e0 = expf(s0 - m), e1 = expf(s1 - m);
  float inv = 1.0f / (e0 + e1);
  float b0 = e0 * inv, b1 = e1 * inv;
  bf16x8 r = ((const bf16x8*)resb)[i];
  f32x4 w0 = ((const f32x4*)v2)[2 * i];
  f32x4 w1 = ((const f32x4*)v2)[2 * i + 1];
  f32x4 o0, o1;
#pragma unroll
  for (int j = 0; j < 4; ++j) {
    o0[j] = b0 * (float)r[j] + b1 * w0[j];
    o1[j] = b0 * (float)r[4 + j] + b1 * w1[j];
  }
  ((f32x4*)out)[2 * i] = o0;
  ((f32x4*)out)[2 * i + 1] = o1;
}

extern "C" void kernel_launch(void* const* d_in, const int* in_sizes, int n_in,
                              void* d_out, int out_size, void* d_ws, size_t ws_size,
                              hipStream_t stream) {
  const float* x   = (const float*)d_in[0];
  const float* v2  = (const float*)d_in[1];
  const float* Wn1 = (const float*)d_in[2];
  const float* Ws1 = (const float*)d_in[3];
  const float* b1  = (const float*)d_in[4];
  const float* Wn2 = (const float*)d_in[5];
  const float* Ws2 = (const float*)d_in[6];
  const float* b2  = (const float*)d_in[7];
  const float* Wa  = (const float*)d_in[8];
  const float* ba  = (const float*)d_in[9];
  const float* att = (const float*)d_in[10];
  const int*  src  = (const int*)d_in[11];
  const int*  dst  = (const int*)d_in[12];
  const int D = in_sizes[4];        // 128
  const int N = in_sizes[0] / D;    // 50000
  const int E = in_sizes[11];       // 640000
  float* out = (float*)d_out;

  char* ws = (char*)d_ws;
  size_t o = 0;
  auto alloc = [&](size_t bytes) -> void* {
    void* p = ws + o;
    o += (bytes + 255) & ~(size_t)255;
    return p;
  };
  int*  cnt    = (int*)alloc((size_t)N * 4);
  int*  offs   = (int*)alloc((size_t)(N + 1) * 4);
  int*  cursor = (int*)alloc((size_t)N * 4);
  int*  ssrc   = (int*)alloc((size_t)E * 4);
  int*  perm   = (int*)alloc((size_t)N * 4);
  bf16* xb     = (bf16*)alloc((size_t)N * D * 2);
  bf16* h1b    = (bf16*)alloc((size_t)N * D * 2);
  bf16* resb   = (bf16*)alloc((size_t)N * D * 2);
  bf16* wb     = (bf16*)alloc((size_t)5 * D * D * 2);
  float* sc    = (float*)alloc(2 * 4);
  int nb = (N + 255) / 256;
  int*  bsum   = (int*)alloc((size_t)nb * 4);
  int*  bhist  = (int*)alloc((size_t)nb * 64 * 4);

  int tilesPerView = (N + 15) / 16;          // 3125
  int attnWaves = 2 * tilesPerView;          // 6250
  int nbA = (attnWaves + 7) / 8;             // 782 blocks (8 waves each)
  float* apart = (float*)alloc((size_t)2 * nbA * 4);

  // fused prologue
  int nbZ = (N + 255) / 256;                 // zero cnt
  int nbW = (5 * D * D + 255) / 256;         // weights -> bf16
  int nbX = (N * D / 8 + 255) / 256;         // x -> bf16
  k_prep<<<nbZ + nbW + nbX, 256, 0, stream>>>(cnt, N, Ws1, Wn1, Ws2, Wn2, Wa, wb,
                                              5 * D * D, x, xb, N * D / 8, nbZ, nbW);

  k_hist<<<(E + 255) / 256, 256, 0, stream>>>(dst, cnt, E);
  k_scan1<<<nb, 256, 0, stream>>>(cnt, bsum, N);
  k_scan2<<<1, 256, 0, stream>>>(bsum, nb);
  k_scan3<<<nb, 256, 0, stream>>>(cnt, bsum, offs, cursor, N);
  // degree sort (contention-free: LDS hist + block-local ranks)
  k_dhist<<<nb, 256, 0, stream>>>(cnt, bhist, N);
  k_dscan<<<1, 64, 0, stream>>>(bhist, nb);
  k_dperm<<<nb, 256, 0, stream>>>(cnt, bhist, perm, N);
  k_scatter<<<(E + 255) / 256, 256, 0, stream>>>(src, dst, cursor, ssrc, E);

  int tiles = (N + 15) / 16;                 // 3125 row tiles
  int layerBlocks = (tiles + 15) / 16;       // 16 waves/block, interleaved

  // layer 1: h1 (bf16) = x@Ws1^T + mean_nb(x)@Wn1^T + b1
  k_layer<0><<<layerBlocks, 1024, 0, stream>>>(xb, offs, ssrc, perm, wb, wb + D * D,
                                               b1, nullptr, h1b, nullptr, N);
  // layer 2: res (bf16) = x + h1 + 0.5*h2
  k_layer<1><<<layerBlocks, 1024, 0, stream>>>(h1b, offs, ssrc, perm, wb + 2 * D * D,
                                               wb + 3 * D * D, b2, x, nullptr, resb, N);
  // fused attention scores over [res, view2], W_attn LDS-staged
  k_attn2<<<nbA, 512, 0, stream>>>(resb, v2, wb + 4 * D * D, ba, att, apart, nbA, N);
  k_score<<<1, 256, 0, stream>>>(apart, sc, nbA);
  // final blend
  k_fin<<<((N * D / 8) + 255) / 256, 256, 0, stream>>>(out, resb, v2, sc,
                                                       1.0f / (float)N, N * D / 8);
}

// Round 15
// 182.200 us; speedup vs baseline: 2.9336x; 1.4182x over previous
//
#include <hip/hip_runtime.h>

#define DD 128

using bf16 = __bf16;
typedef __bf16 bf16x8 __attribute__((ext_vector_type(8)));
typedef float f32x4 __attribute__((ext_vector_type(4)));

__device__ inline bf16x8 cvt8(const float* p) {
  f32x4 v0 = *(const f32x4*)p;
  f32x4 v1 = *(const f32x4*)(p + 4);
  bf16x8 r;
  r[0] = (bf16)v0[0]; r[1] = (bf16)v0[1]; r[2] = (bf16)v0[2]; r[3] = (bf16)v0[3];
  r[4] = (bf16)v1[0]; r[5] = (bf16)v1[1]; r[6] = (bf16)v1[2]; r[7] = (bf16)v1[3];
  return r;
}

// fast tanh: 1 - 2/(e^{2x}+1); v_exp + v_rcp, saturates correctly at +-1
__device__ inline float ftanh(float x) {
  float e2 = __expf(2.0f * x);
  return 1.0f - 2.0f * __builtin_amdgcn_rcpf(e2 + 1.0f);
}

// XOR swizzle for [128 rows][256 B] LDS tiles (G4)
__device__ inline int swz(int o) { return o ^ (((o >> 8) & 7) << 4); }

// ---- fused prologue: zero cnt | weights->bf16 | x->bf16 ------------------
__global__ void k_prep(int* __restrict__ cnt, int N,
                       const float* __restrict__ w0, const float* __restrict__ w1,
                       const float* __restrict__ w2, const float* __restrict__ w3,
                       const float* __restrict__ w4, bf16* __restrict__ wb, int totalW,
                       const float* __restrict__ x, bf16* __restrict__ xb, int total8,
                       int nbZ, int nbW) {
  int b = blockIdx.x;
  if (b < nbZ) {
    int i = b * 256 + threadIdx.x;
    if (i < N) cnt[i] = 0;
  } else if (b < nbZ + nbW) {
    int i = (b - nbZ) * 256 + threadIdx.x;
    if (i < totalW) {
      int m = i >> 14;           // DD*DD = 16384
      int r = i & 16383;
      const float* s = m == 0 ? w0 : m == 1 ? w1 : m == 2 ? w2 : m == 3 ? w3 : w4;
      wb[i] = (bf16)s[r];
    }
  } else {
    int i = (b - nbZ - nbW) * 256 + threadIdx.x;
    if (i < total8) *(bf16x8*)(xb + (size_t)i * 8) = cvt8(x + (size_t)i * 8);
  }
}

// ---- CSR build ----------------------------------------------------------
__global__ void k_hist(const int* __restrict__ dst, int* __restrict__ cnt, int E) {
  int e = blockIdx.x * 256 + threadIdx.x;
  if (e < E) atomicAdd(&cnt[dst[e]], 1);
}

__global__ __launch_bounds__(256) void k_scan1(const int* __restrict__ cnt,
                                               int* __restrict__ bsum, int N) {
  __shared__ int sm[256];
  int t = threadIdx.x;
  int i = blockIdx.x * 256 + t;
  sm[t] = (i < N) ? cnt[i] : 0;
  __syncthreads();
#pragma unroll
  for (int d = 128; d > 0; d >>= 1) {
    if (t < d) sm[t] += sm[t + d];
    __syncthreads();
  }
  if (t == 0) bsum[blockIdx.x] = sm[0];
}

__global__ __launch_bounds__(256) void k_scan2(int* __restrict__ bsum, int nb) {
  __shared__ int sm[256];
  int t = threadIdx.x;
  int v = (t < nb) ? bsum[t] : 0;
  sm[t] = v;
  __syncthreads();
#pragma unroll
  for (int d = 1; d < 256; d <<= 1) {
    int u = (t >= d) ? sm[t - d] : 0;
    __syncthreads();
    sm[t] += u;
    __syncthreads();
  }
  if (t < nb) bsum[t] = sm[t] - v;   // exclusive prefix
}

__global__ __launch_bounds__(256) void k_scan3(const int* __restrict__ cnt,
                                               const int* __restrict__ bsum,
                                               int* __restrict__ offs,
                                               int* __restrict__ cursor, int N) {
  __shared__ int sm[256];
  int t = threadIdx.x;
  int i = blockIdx.x * 256 + t;
  int v = (i < N) ? cnt[i] : 0;
  sm[t] = v;
  __syncthreads();
#pragma unroll
  for (int d = 1; d < 256; d <<= 1) {
    int u = (t >= d) ? sm[t - d] : 0;
    __syncthreads();
    sm[t] += u;
    __syncthreads();
  }
  int incl = sm[t];
  int base = bsum[blockIdx.x];
  if (i < N) {
    int ex = base + incl - v;
    offs[i] = ex;
    cursor[i] = ex;
    if (i == N - 1) offs[N] = base + incl;
  }
}

__global__ void k_scatter(const int* __restrict__ src, const int* __restrict__ dst,
                          int* __restrict__ cursor, int* __restrict__ ssrc, int E) {
  int e = blockIdx.x * 256 + threadIdx.x;
  if (e < E) {
    int d = dst[e];
    int p = atomicAdd(&cursor[d], 1);
    ssrc[p] = src[e];
  }
}

// ---- fused SAGE layer: aggregate + GEMM ---------------------------------
// Block = 1024 threads (16 waves), Ws+Wn staged in 64 KB swizzled LDS.
// Grid = 256 blocks (1/CU); tile = wv*gridDim + blockIdx spreads active
// waves over ALL CUs (<=13/CU) instead of 16 waves on 196 CUs (R11).
// MODE 0: H1out = (bf16)v
// MODE 1: Resb = (bf16)(Xres + h1 + 0.5*v)
template <int MODE>
__global__ __launch_bounds__(1024, 1) void k_layer(const bf16* __restrict__ Hb,
                                                   const int* __restrict__ offs,
                                                   const int* __restrict__ ssrc,
                                                   const bf16* __restrict__ Wsb,
                                                   const bf16* __restrict__ Wnb,
                                                   const float* __restrict__ bias,
                                                   const float* __restrict__ Xres,
                                                   bf16* __restrict__ H1out,
                                                   bf16* __restrict__ Resb, int N) {
  __shared__ char smem[65536];   // [2][128 rows][256 B], swizzled
  int t = threadIdx.x;
#pragma unroll
  for (int m = 0; m < 2; ++m) {
    const bf16* wsrc = m ? Wnb : Wsb;
#pragma unroll
    for (int it = 0; it < 2; ++it) {
      int o = (it * 1024 + t) * 16;         // linear byte offset in matrix
      *(bf16x8*)(smem + m * 32768 + swz(o)) = *(const bf16x8*)(wsrc + o / 2);
    }
  }
  __syncthreads();

  int wv = t >> 6;
  int lane = t & 63;
  int tile = wv * gridDim.x + blockIdx.x;   // CU-spread tile mapping
  int n0 = tile << 4;
  if (n0 >= N) return;
  int lr = lane & 15;
  int g = lane >> 4;
  int lk = g << 3;                          // k offset in elems (8-elem chunk)

  int node = n0 + lr;

  // A1 (self) fragments
  const bf16* a1p = Hb + (size_t)node * DD + lk;
  bf16x8 a1[4];
#pragma unroll
  for (int kk = 0; kk < 4; ++kk) a1[kk] = *(const bf16x8*)(a1p + kk * 32);

  // aggregate neighbor mean into A2 fragments (f32 acc)
  int beg = offs[node], end = offs[node + 1];
  float acc[4][8];
#pragma unroll
  for (int kk = 0; kk < 4; ++kk)
#pragma unroll
    for (int j = 0; j < 8; ++j) acc[kk][j] = 0.f;
  for (int i = beg; i < end; ++i) {
    int s = ssrc[i];
    const bf16* hp = Hb + (size_t)s * DD + lk;
#pragma unroll
    for (int kk = 0; kk < 4; ++kk) {
      bf16x8 v = *(const bf16x8*)(hp + kk * 32);
#pragma unroll
      for (int j = 0; j < 8; ++j) acc[kk][j] += (float)v[j];
    }
  }
  float inv = (end > beg) ? 1.0f / (float)(end - beg) : 0.f;
  bf16x8 a2[4];
#pragma unroll
  for (int kk = 0; kk < 4; ++kk)
#pragma unroll
    for (int j = 0; j < 8; ++j) a2[kk][j] = (bf16)(acc[kk][j] * inv);

  int rb = n0 + (g << 2);
#pragma unroll
  for (int j = 0; j < 8; ++j) {
    int row = j * 16 + lr;
    int rbase = row * 256 + lk * 2;         // byte offset of this lane's chunk
    f32x4 cs = {0.f, 0.f, 0.f, 0.f};
    f32x4 cn = {0.f, 0.f, 0.f, 0.f};
#pragma unroll
    for (int kk = 0; kk < 4; ++kk) {
      int ro = swz(rbase + kk * 64);
      bf16x8 bs = *(const bf16x8*)(smem + ro);
      bf16x8 bn = *(const bf16x8*)(smem + 32768 + ro);
      cs = __builtin_amdgcn_mfma_f32_16x16x32_bf16(a1[kk], bs, cs, 0, 0, 0);
      cn = __builtin_amdgcn_mfma_f32_16x16x32_bf16(a2[kk], bn, cn, 0, 0, 0);
    }
    int col = j * 16 + lr;
    float bb = bias[col];
#pragma unroll
    for (int r = 0; r < 4; ++r) {
      size_t idx = (size_t)(rb + r) * DD + col;
      float v = cs[r] + cn[r] + bb;
      if (MODE == 0) H1out[idx] = (bf16)v;
      else           Resb[idx] = (bf16)(Xres[idx] + (float)Hb[idx] + 0.5f * v);
    }
  }
}

// ---- fused attention scores, LDS-staged W_attn --------------------------
// Block = 512 threads (8 waves); Wa staged in 32 KB swizzled LDS.
// view 0 reads res (bf16), view 1 reads v2 (f32).
__global__ __launch_bounds__(512, 4) void k_attn2(const bf16* __restrict__ resb,
                                                  const float* __restrict__ v2f,
                                                  const bf16* __restrict__ Wab,
                                                  const float* __restrict__ bias,
                                                  const float* __restrict__ att,
                                                  float* __restrict__ partial,
                                                  int nbA, int N) {
  __shared__ char smem[32768];   // [128 rows][256 B], swizzled
  __shared__ float smr[8];
  int t = threadIdx.x;
#pragma unroll
  for (int it = 0; it < 4; ++it) {
    int o = (it * 512 + t) * 16;            // linear byte offset in matrix
    *(bf16x8*)(smem + swz(o)) = *(const bf16x8*)(Wab + o / 2);
  }
  __syncthreads();

  int wv = t >> 6;
  int lane = t & 63;
  int gwid = blockIdx.x * 8 + wv;
  int view = gwid & 1;
  int tile = gwid >> 1;
  int n0 = tile << 4;
  float part = 0.f;
  if (n0 < N) {
    int lr = lane & 15;
    int lk = (lane >> 4) << 3;
    bf16x8 a[4];
    if (view) {
      const float* ap = v2f + (size_t)(n0 + lr) * DD + lk;
#pragma unroll
      for (int kk = 0; kk < 4; ++kk) a[kk] = cvt8(ap + kk * 32);
    } else {
      const bf16* ap = resb + (size_t)(n0 + lr) * DD + lk;
#pragma unroll
      for (int kk = 0; kk < 4; ++kk) a[kk] = *(const bf16x8*)(ap + kk * 32);
    }
#pragma unroll
    for (int j = 0; j < 8; ++j) {
      int row = j * 16 + lr;
      int rbase = row * 256 + lk * 2;
      f32x4 c = {0.f, 0.f, 0.f, 0.f};
#pragma unroll
      for (int kk = 0; kk < 4; ++kk) {
        bf16x8 bw = *(const bf16x8*)(smem + swz(rbase + kk * 64));
        c = __builtin_amdgcn_mfma_f32_16x16x32_bf16(a[kk], bw, c, 0, 0, 0);
      }
      int col = j * 16 + lr;
      float aw = att[col], bb = bias[col];
#pragma unroll
      for (int r = 0; r < 4; ++r) part += aw * ftanh(c[r] + bb);
    }
  }
#pragma unroll
  for (int d = 1; d < 64; d <<= 1) part += __shfl_xor(part, d);
  if (lane == 0) smr[wv] = part;
  __syncthreads();
  if (t == 0) {
    partial[blockIdx.x]       = smr[0] + smr[2] + smr[4] + smr[6];  // view 0
    partial[nbA + blockIdx.x] = smr[1] + smr[3] + smr[5] + smr[7];  // view 1
  }
}

// ---- reduce partials -> scores[2] ---------------------------------------
__global__ __launch_bounds__(256) void k_score(const float* __restrict__ partial,
                                               float* __restrict__ scores, int nbA) {
  __shared__ float sm[256];
  int t = threadIdx.x;
#pragma unroll
  for (int v = 0; v < 2; ++v) {
    float s = 0.f;
    for (int i = t; i < nbA; i += 256) s += partial[v * nbA + i];
    sm[t] = s;
    __syncthreads();
#pragma unroll
    for (int d = 128; d > 0; d >>= 1) {
      if (t < d) sm[t] += sm[t + d];
      __syncthreads();
    }
    if (t == 0) scores[v] = sm[0];
    __syncthreads();
  }
}

// ---- final blend: out = b0*res(bf16) + b1*view2(f32) --------------------
__global__ void k_fin(float* __restrict__ out, const bf16* __restrict__ resb,
                      const float* __restrict__ v2,
                      const float* __restrict__ scores, float invN, int total8) {
  int i = blockIdx.x * 256 + threadIdx.x;
  if (i >= total8) return;
  float s0 = scores[0] * invN, s1 = scores[1] * invN;
  float m = fmaxf(s0, s1);
  float e0 = expf(s0 - m), e1 = expf(s1 - m);
  float inv = 1.0f / (e0 + e1);
  float b0 = e0 * inv, b1 = e1 * inv;
  bf16x8 r = ((const bf16x8*)resb)[i];
  f32x4 w0 = ((const f32x4*)v2)[2 * i];
  f32x4 w1 = ((const f32x4*)v2)[2 * i + 1];
  f32x4 o0, o1;
#pragma unroll
  for (int j = 0; j < 4; ++j) {
    o0[j] = b0 * (float)r[j] + b1 * w0[j];
    o1[j] = b0 * (float)r[4 + j] + b1 * w1[j];
  }
  ((f32x4*)out)[2 * i] = o0;
  ((f32x4*)out)[2 * i + 1] = o1;
}

extern "C" void kernel_launch(void* const* d_in, const int* in_sizes, int n_in,
                              void* d_out, int out_size, void* d_ws, size_t ws_size,
                              hipStream_t stream) {
  const float* x   = (const float*)d_in[0];
  const float* v2  = (const float*)d_in[1];
  const float* Wn1 = (const float*)d_in[2];
  const float* Ws1 = (const float*)d_in[3];
  const float* b1  = (const float*)d_in[4];
  const float* Wn2 = (const float*)d_in[5];
  const float* Ws2 = (const float*)d_in[6];
  const float* b2  = (const float*)d_in[7];
  const float* Wa  = (const float*)d_in[8];
  const float* ba  = (const float*)d_in[9];
  const float* att = (const float*)d_in[10];
  const int*  src  = (const int*)d_in[11];
  const int*  dst  = (const int*)d_in[12];
  const int D = in_sizes[4];        // 128
  const int N = in_sizes[0] / D;    // 50000
  const int E = in_sizes[11];       // 640000
  float* out = (float*)d_out;

  char* ws = (char*)d_ws;
  size_t o = 0;
  auto alloc = [&](size_t bytes) -> void* {
    void* p = ws + o;
    o += (bytes + 255) & ~(size_t)255;
    return p;
  };
  int*  cnt    = (int*)alloc((size_t)N * 4);
  int*  offs   = (int*)alloc((size_t)(N + 1) * 4);
  int*  cursor = (int*)alloc((size_t)N * 4);
  int*  ssrc   = (int*)alloc((size_t)E * 4);
  bf16* xb     = (bf16*)alloc((size_t)N * D * 2);
  bf16* h1b    = (bf16*)alloc((size_t)N * D * 2);
  bf16* resb   = (bf16*)alloc((size_t)N * D * 2);
  bf16* wb     = (bf16*)alloc((size_t)5 * D * D * 2);
  float* sc    = (float*)alloc(2 * 4);
  int nb = (N + 255) / 256;
  int*  bsum   = (int*)alloc((size_t)nb * 4);

  int tilesPerView = (N + 15) / 16;          // 3125
  int attnWaves = 2 * tilesPerView;          // 6250
  int nbA = (attnWaves + 7) / 8;             // 782 blocks (8 waves each)
  float* apart = (float*)alloc((size_t)2 * nbA * 4);

  // fused prologue
  int nbZ = (N + 255) / 256;                 // zero cnt
  int nbW = (5 * D * D + 255) / 256;         // weights -> bf16
  int nbX = (N * D / 8 + 255) / 256;         // x -> bf16
  k_prep<<<nbZ + nbW + nbX, 256, 0, stream>>>(cnt, N, Ws1, Wn1, Ws2, Wn2, Wa, wb,
                                              5 * D * D, x, xb, N * D / 8, nbZ, nbW);

  k_hist<<<(E + 255) / 256, 256, 0, stream>>>(dst, cnt, E);
  k_scan1<<<nb, 256, 0, stream>>>(cnt, bsum, N);
  k_scan2<<<1, 256, 0, stream>>>(bsum, nb);
  k_scan3<<<nb, 256, 0, stream>>>(cnt, bsum, offs, cursor, N);
  k_scatter<<<(E + 255) / 256, 256, 0, stream>>>(src, dst, cursor, ssrc, E);

  int layerBlocks = 256;                     // 1 block/CU; waves CU-spread

  // layer 1: h1 (bf16) = x@Ws1^T + mean_nb(x)@Wn1^T + b1
  k_layer<0><<<layerBlocks, 1024, 0, stream>>>(xb, offs, ssrc, wb, wb + D * D, b1,
                                               nullptr, h1b, nullptr, N);
  // layer 2: res (bf16) = x + h1 + 0.5*h2
  k_layer<1><<<layerBlocks, 1024, 0, stream>>>(h1b, offs, ssrc, wb + 2 * D * D,
                                               wb + 3 * D * D, b2, x, nullptr, resb, N);
  // fused attention scores over [res, view2], W_attn LDS-staged
  k_attn2<<<nbA, 512, 0, stream>>>(resb, v2, wb + 4 * D * D, ba, att, apart, nbA, N);
  k_score<<<1, 256, 0, stream>>>(apart, sc, nbA);
  // final blend
  k_fin<<<((N * D / 8) + 255) / 256, 256, 0, stream>>>(out, resb, v2, sc,
                                                       1.0f / (float)N, N * D / 8);
}

// Round 16
// 181.683 us; speedup vs baseline: 2.9419x; 1.0028x over previous
//
#include <hip/hip_runtime.h>

#define DD 128

using bf16 = __bf16;
typedef __bf16 bf16x8 __attribute__((ext_vector_type(8)));
typedef float f32x4 __attribute__((ext_vector_type(4)));

__device__ inline bf16x8 cvt8(const float* p) {
  f32x4 v0 = *(const f32x4*)p;
  f32x4 v1 = *(const f32x4*)(p + 4);
  bf16x8 r;
  r[0] = (bf16)v0[0]; r[1] = (bf16)v0[1]; r[2] = (bf16)v0[2]; r[3] = (bf16)v0[3];
  r[4] = (bf16)v1[0]; r[5] = (bf16)v1[1]; r[6] = (bf16)v1[2]; r[7] = (bf16)v1[3];
  return r;
}

// fast tanh: 1 - 2/(e^{2x}+1); v_exp + v_rcp, saturates correctly at +-1
__device__ inline float ftanh(float x) {
  float e2 = __expf(2.0f * x);
  return 1.0f - 2.0f * __builtin_amdgcn_rcpf(e2 + 1.0f);
}

// XOR swizzle for [128 rows][256 B] LDS tiles (G4)
__device__ inline int swz(int o) { return o ^ (((o >> 8) & 7) << 4); }

// ---- fused prologue: zero cnt | weights->bf16 | x->bf16 ------------------
__global__ void k_prep(int* __restrict__ cnt, int N,
                       const float* __restrict__ w0, const float* __restrict__ w1,
                       const float* __restrict__ w2, const float* __restrict__ w3,
                       const float* __restrict__ w4, bf16* __restrict__ wb, int totalW,
                       const float* __restrict__ x, bf16* __restrict__ xb, int total8,
                       int nbZ, int nbW) {
  int b = blockIdx.x;
  if (b < nbZ) {
    int i = b * 256 + threadIdx.x;
    if (i < N) cnt[i] = 0;
  } else if (b < nbZ + nbW) {
    int i = (b - nbZ) * 256 + threadIdx.x;
    if (i < totalW) {
      int m = i >> 14;           // DD*DD = 16384
      int r = i & 16383;
      const float* s = m == 0 ? w0 : m == 1 ? w1 : m == 2 ? w2 : m == 3 ? w3 : w4;
      wb[i] = (bf16)s[r];
    }
  } else {
    int i = (b - nbZ - nbW) * 256 + threadIdx.x;
    if (i < total8) *(bf16x8*)(xb + (size_t)i * 8) = cvt8(x + (size_t)i * 8);
  }
}

// ---- CSR build ----------------------------------------------------------
__global__ void k_hist(const int* __restrict__ dst, int* __restrict__ cnt, int E) {
  int e = blockIdx.x * 256 + threadIdx.x;
  if (e < E) atomicAdd(&cnt[dst[e]], 1);
}

__global__ __launch_bounds__(256) void k_scan1(const int* __restrict__ cnt,
                                               int* __restrict__ bsum, int N) {
  __shared__ int sm[256];
  int t = threadIdx.x;
  int i = blockIdx.x * 256 + t;
  sm[t] = (i < N) ? cnt[i] : 0;
  __syncthreads();
#pragma unroll
  for (int d = 128; d > 0; d >>= 1) {
    if (t < d) sm[t] += sm[t + d];
    __syncthreads();
  }
  if (t == 0) bsum[blockIdx.x] = sm[0];
}

__global__ __launch_bounds__(256) void k_scan2(int* __restrict__ bsum, int nb) {
  __shared__ int sm[256];
  int t = threadIdx.x;
  int v = (t < nb) ? bsum[t] : 0;
  sm[t] = v;
  __syncthreads();
#pragma unroll
  for (int d = 1; d < 256; d <<= 1) {
    int u = (t >= d) ? sm[t - d] : 0;
    __syncthreads();
    sm[t] += u;
    __syncthreads();
  }
  if (t < nb) bsum[t] = sm[t] - v;   // exclusive prefix
}

__global__ __launch_bounds__(256) void k_scan3(const int* __restrict__ cnt,
                                               const int* __restrict__ bsum,
                                               int* __restrict__ offs,
                                               int* __restrict__ cursor, int N) {
  __shared__ int sm[256];
  int t = threadIdx.x;
  int i = blockIdx.x * 256 + t;
  int v = (i < N) ? cnt[i] : 0;
  sm[t] = v;
  __syncthreads();
#pragma unroll
  for (int d = 1; d < 256; d <<= 1) {
    int u = (t >= d) ? sm[t - d] : 0;
    __syncthreads();
    sm[t] += u;
    __syncthreads();
  }
  int incl = sm[t];
  int base = bsum[blockIdx.x];
  if (i < N) {
    int ex = base + incl - v;
    offs[i] = ex;
    cursor[i] = ex;
    if (i == N - 1) offs[N] = base + incl;
  }
}

__global__ void k_scatter(const int* __restrict__ src, const int* __restrict__ dst,
                          int* __restrict__ cursor, int* __restrict__ ssrc, int E) {
  int e = blockIdx.x * 256 + threadIdx.x;
  if (e < E) {
    int d = dst[e];
    int p = atomicAdd(&cursor[d], 1);
    ssrc[p] = src[e];
  }
}

// ---- fused SAGE layer: aggregate + GEMM ---------------------------------
// Block = 1024 threads (16 waves), Ws+Wn staged in 64 KB swizzled LDS.
// Grid = 256 blocks; tile = wv*gridDim + blockIdx (CU-spread).
// Gather loop is 1-deep software-pipelined: next edge's row (4x16B) and
// index are in flight while the current row accumulates (breaks the
// ssrc->row serial chain; R9's 4x unroll was too much register pressure).
// MODE 0: H1out = (bf16)v
// MODE 1: Resb = (bf16)(Xres + h1 + 0.5*v)
template <int MODE>
__global__ __launch_bounds__(1024, 1) void k_layer(const bf16* __restrict__ Hb,
                                                   const int* __restrict__ offs,
                                                   const int* __restrict__ ssrc,
                                                   const bf16* __restrict__ Wsb,
                                                   const bf16* __restrict__ Wnb,
                                                   const float* __restrict__ bias,
                                                   const float* __restrict__ Xres,
                                                   bf16* __restrict__ H1out,
                                                   bf16* __restrict__ Resb, int N) {
  __shared__ char smem[65536];   // [2][128 rows][256 B], swizzled
  int t = threadIdx.x;
#pragma unroll
  for (int m = 0; m < 2; ++m) {
    const bf16* wsrc = m ? Wnb : Wsb;
#pragma unroll
    for (int it = 0; it < 2; ++it) {
      int o = (it * 1024 + t) * 16;         // linear byte offset in matrix
      *(bf16x8*)(smem + m * 32768 + swz(o)) = *(const bf16x8*)(wsrc + o / 2);
    }
  }
  __syncthreads();

  int wv = t >> 6;
  int lane = t & 63;
  int tile = wv * gridDim.x + blockIdx.x;   // CU-spread tile mapping
  int n0 = tile << 4;
  if (n0 >= N) return;
  int lr = lane & 15;
  int g = lane >> 4;
  int lk = g << 3;                          // k offset in elems (8-elem chunk)

  int node = n0 + lr;

  // A1 (self) fragments
  const bf16* a1p = Hb + (size_t)node * DD + lk;
  bf16x8 a1[4];
#pragma unroll
  for (int kk = 0; kk < 4; ++kk) a1[kk] = *(const bf16x8*)(a1p + kk * 32);

  // aggregate neighbor mean into A2 fragments (f32 acc), 1-deep pipelined
  int beg = offs[node], end = offs[node + 1];
  float acc[4][8];
#pragma unroll
  for (int kk = 0; kk < 4; ++kk)
#pragma unroll
    for (int j = 0; j < 8; ++j) acc[kk][j] = 0.f;

  if (beg < end) {
    int s = ssrc[beg];
    const bf16* hp = Hb + (size_t)s * DD + lk;
    bf16x8 cur[4];
#pragma unroll
    for (int kk = 0; kk < 4; ++kk) cur[kk] = *(const bf16x8*)(hp + kk * 32);
    for (int i = beg + 1; i < end; ++i) {
      int s2 = ssrc[i];                     // issue next index + row loads
      const bf16* hp2 = Hb + (size_t)s2 * DD + lk;
      bf16x8 nxt[4];
#pragma unroll
      for (int kk = 0; kk < 4; ++kk) nxt[kk] = *(const bf16x8*)(hp2 + kk * 32);
#pragma unroll
      for (int kk = 0; kk < 4; ++kk)        // accumulate previous row
#pragma unroll
        for (int j = 0; j < 8; ++j) acc[kk][j] += (float)cur[kk][j];
#pragma unroll
      for (int kk = 0; kk < 4; ++kk) cur[kk] = nxt[kk];
    }
#pragma unroll
    for (int kk = 0; kk < 4; ++kk)          // last row
#pragma unroll
      for (int j = 0; j < 8; ++j) acc[kk][j] += (float)cur[kk][j];
  }
  float inv = (end > beg) ? 1.0f / (float)(end - beg) : 0.f;
  bf16x8 a2[4];
#pragma unroll
  for (int kk = 0; kk < 4; ++kk)
#pragma unroll
    for (int j = 0; j < 8; ++j) a2[kk][j] = (bf16)(acc[kk][j] * inv);

  int rb = n0 + (g << 2);
#pragma unroll
  for (int j = 0; j < 8; ++j) {
    int row = j * 16 + lr;
    int rbase = row * 256 + lk * 2;         // byte offset of this lane's chunk
    f32x4 cs = {0.f, 0.f, 0.f, 0.f};
    f32x4 cn = {0.f, 0.f, 0.f, 0.f};
#pragma unroll
    for (int kk = 0; kk < 4; ++kk) {
      int ro = swz(rbase + kk * 64);
      bf16x8 bs = *(const bf16x8*)(smem + ro);
      bf16x8 bn = *(const bf16x8*)(smem + 32768 + ro);
      cs = __builtin_amdgcn_mfma_f32_16x16x32_bf16(a1[kk], bs, cs, 0, 0, 0);
      cn = __builtin_amdgcn_mfma_f32_16x16x32_bf16(a2[kk], bn, cn, 0, 0, 0);
    }
    int col = j * 16 + lr;
    float bb = bias[col];
#pragma unroll
    for (int r = 0; r < 4; ++r) {
      size_t idx = (size_t)(rb + r) * DD + col;
      float v = cs[r] + cn[r] + bb;
      if (MODE == 0) H1out[idx] = (bf16)v;
      else           Resb[idx] = (bf16)(Xres[idx] + (float)Hb[idx] + 0.5f * v);
    }
  }
}

// ---- fused attention scores, LDS-staged W_attn --------------------------
// Block = 512 threads (8 waves); Wa staged in 32 KB swizzled LDS.
// view 0 reads res (bf16), view 1 reads v2 (f32).
__global__ __launch_bounds__(512, 4) void k_attn2(const bf16* __restrict__ resb,
                                                  const float* __restrict__ v2f,
                                                  const bf16* __restrict__ Wab,
                                                  const float* __restrict__ bias,
                                                  const float* __restrict__ att,
                                                  float* __restrict__ partial,
                                                  int nbA, int N) {
  __shared__ char smem[32768];   // [128 rows][256 B], swizzled
  __shared__ float smr[8];
  int t = threadIdx.x;
#pragma unroll
  for (int it = 0; it < 4; ++it) {
    int o = (it * 512 + t) * 16;            // linear byte offset in matrix
    *(bf16x8*)(smem + swz(o)) = *(const bf16x8*)(Wab + o / 2);
  }
  __syncthreads();

  int wv = t >> 6;
  int lane = t & 63;
  int gwid = blockIdx.x * 8 + wv;
  int view = gwid & 1;
  int tile = gwid >> 1;
  int n0 = tile << 4;
  float part = 0.f;
  if (n0 < N) {
    int lr = lane & 15;
    int lk = (lane >> 4) << 3;
    bf16x8 a[4];
    if (view) {
      const float* ap = v2f + (size_t)(n0 + lr) * DD + lk;
#pragma unroll
      for (int kk = 0; kk < 4; ++kk) a[kk] = cvt8(ap + kk * 32);
    } else {
      const bf16* ap = resb + (size_t)(n0 + lr) * DD + lk;
#pragma unroll
      for (int kk = 0; kk < 4; ++kk) a[kk] = *(const bf16x8*)(ap + kk * 32);
    }
#pragma unroll
    for (int j = 0; j < 8; ++j) {
      int row = j * 16 + lr;
      int rbase = row * 256 + lk * 2;
      f32x4 c = {0.f, 0.f, 0.f, 0.f};
#pragma unroll
      for (int kk = 0; kk < 4; ++kk) {
        bf16x8 bw = *(const bf16x8*)(smem + swz(rbase + kk * 64));
        c = __builtin_amdgcn_mfma_f32_16x16x32_bf16(a[kk], bw, c, 0, 0, 0);
      }
      int col = j * 16 + lr;
      float aw = att[col], bb = bias[col];
#pragma unroll
      for (int r = 0; r < 4; ++r) part += aw * ftanh(c[r] + bb);
    }
  }
#pragma unroll
  for (int d = 1; d < 64; d <<= 1) part += __shfl_xor(part, d);
  if (lane == 0) smr[wv] = part;
  __syncthreads();
  if (t == 0) {
    partial[blockIdx.x]       = smr[0] + smr[2] + smr[4] + smr[6];  // view 0
    partial[nbA + blockIdx.x] = smr[1] + smr[3] + smr[5] + smr[7];  // view 1
  }
}

// ---- reduce partials -> scores[2] ---------------------------------------
__global__ __launch_bounds__(256) void k_score(const float* __restrict__ partial,
                                               float* __restrict__ scores, int nbA) {
  __shared__ float sm[256];
  int t = threadIdx.x;
#pragma unroll
  for (int v = 0; v < 2; ++v) {
    float s = 0.f;
    for (int i = t; i < nbA; i += 256) s += partial[v * nbA + i];
    sm[t] = s;
    __syncthreads();
#pragma unroll
    for (int d = 128; d > 0; d >>= 1) {
      if (t < d) sm[t] += sm[t + d];
      __syncthreads();
    }
    if (t == 0) scores[v] = sm[0];
    __syncthreads();
  }
}

// ---- final blend: out = b0*res(bf16) + b1*view2(f32) --------------------
__global__ void k_fin(float* __restrict__ out, const bf16* __restrict__ resb,
                      const float* __restrict__ v2,
                      const float* __restrict__ scores, float invN, int total8) {
  int i = blockIdx.x * 256 + threadIdx.x;
  if (i >= total8) return;
  float s0 = scores[0] * invN, s1 = scores[1] * invN;
  float m = fmaxf(s0, s1);
  float e0 = expf(s0 - m), e1 = expf(s1 - m);
  float inv = 1.0f / (e0 + e1);
  float b0 = e0 * inv, b1 = e1 * inv;
  bf16x8 r = ((const bf16x8*)resb)[i];
  f32x4 w0 = ((const f32x4*)v2)[2 * i];
  f32x4 w1 = ((const f32x4*)v2)[2 * i + 1];
  f32x4 o0, o1;
#pragma unroll
  for (int j = 0; j < 4; ++j) {
    o0[j] = b0 * (float)r[j] + b1 * w0[j];
    o1[j] = b0 * (float)r[4 + j] + b1 * w1[j];
  }
  ((f32x4*)out)[2 * i] = o0;
  ((f32x4*)out)[2 * i + 1] = o1;
}

extern "C" void kernel_launch(void* const* d_in, const int* in_sizes, int n_in,
                              void* d_out, int out_size, void* d_ws, size_t ws_size,
                              hipStream_t stream) {
  const float* x   = (const float*)d_in[0];
  const float* v2  = (const float*)d_in[1];
  const float* Wn1 = (const float*)d_in[2];
  const float* Ws1 = (const float*)d_in[3];
  const float* b1  = (const float*)d_in[4];
  const float* Wn2 = (const float*)d_in[5];
  const float* Ws2 = (const float*)d_in[6];
  const float* b2  = (const float*)d_in[7];
  const float* Wa  = (const float*)d_in[8];
  const float* ba  = (const float*)d_in[9];
  const float* att = (const float*)d_in[10];
  const int*  src  = (const int*)d_in[11];
  const int*  dst  = (const int*)d_in[12];
  const int D = in_sizes[4];        // 128
  const int N = in_sizes[0] / D;    // 50000
  const int E = in_sizes[11];       // 640000
  float* out = (float*)d_out;

  char* ws = (char*)d_ws;
  size_t o = 0;
  auto alloc = [&](size_t bytes) -> void* {
    void* p = ws + o;
    o += (bytes + 255) & ~(size_t)255;
    return p;
  };
  int*  cnt    = (int*)alloc((size_t)N * 4);
  int*  offs   = (int*)alloc((size_t)(N + 1) * 4);
  int*  cursor = (int*)alloc((size_t)N * 4);
  int*  ssrc   = (int*)alloc((size_t)E * 4);
  bf16* xb     = (bf16*)alloc((size_t)N * D * 2);
  bf16* h1b    = (bf16*)alloc((size_t)N * D * 2);
  bf16* resb   = (bf16*)alloc((size_t)N * D * 2);
  bf16* wb     = (bf16*)alloc((size_t)5 * D * D * 2);
  float* sc    = (float*)alloc(2 * 4);
  int nb = (N + 255) / 256;
  int*  bsum   = (int*)alloc((size_t)nb * 4);

  int tilesPerView = (N + 15) / 16;          // 3125
  int attnWaves = 2 * tilesPerView;          // 6250
  int nbA = (attnWaves + 7) / 8;             // 782 blocks (8 waves each)
  float* apart = (float*)alloc((size_t)2 * nbA * 4);

  // fused prologue
  int nbZ = (N + 255) / 256;                 // zero cnt
  int nbW = (5 * D * D + 255) / 256;         // weights -> bf16
  int nbX = (N * D / 8 + 255) / 256;         // x -> bf16
  k_prep<<<nbZ + nbW + nbX, 256, 0, stream>>>(cnt, N, Ws1, Wn1, Ws2, Wn2, Wa, wb,
                                              5 * D * D, x, xb, N * D / 8, nbZ, nbW);

  k_hist<<<(E + 255) / 256, 256, 0, stream>>>(dst, cnt, E);
  k_scan1<<<nb, 256, 0, stream>>>(cnt, bsum, N);
  k_scan2<<<1, 256, 0, stream>>>(bsum, nb);
  k_scan3<<<nb, 256, 0, stream>>>(cnt, bsum, offs, cursor, N);
  k_scatter<<<(E + 255) / 256, 256, 0, stream>>>(src, dst, cursor, ssrc, E);

  int layerBlocks = 256;                     // 1 block/CU; waves CU-spread

  // layer 1: h1 (bf16) = x@Ws1^T + mean_nb(x)@Wn1^T + b1
  k_layer<0><<<layerBlocks, 1024, 0, stream>>>(xb, offs, ssrc, wb, wb + D * D, b1,
                                               nullptr, h1b, nullptr, N);
  // layer 2: res (bf16) = x + h1 + 0.5*h2
  k_layer<1><<<layerBlocks, 1024, 0, stream>>>(h1b, offs, ssrc, wb + 2 * D * D,
                                               wb + 3 * D * D, b2, x, nullptr, resb, N);
  // fused attention scores over [res, view2], W_attn LDS-staged
  k_attn2<<<nbA, 512, 0, stream>>>(resb, v2, wb + 4 * D * D, ba, att, apart, nbA, N);
  k_score<<<1, 256, 0, stream>>>(apart, sc, nbA);
  // final blend
  k_fin<<<((N * D / 8) + 255) / 256, 256, 0, stream>>>(out, resb, v2, sc,
                                                       1.0f / (float)N, N * D / 8);
}